// Round 7
// baseline (448.076 us; speedup 1.0000x reference)
//
#include <hip/hip_runtime.h>

#define NL 16384          // row length
#define NB 64             // rows
#define NSEG 4            // blocks per row
#define SEG (NL / NSEG)   // 4096 elements per block
#define NT 1024           // threads per block (16 waves)
#define NC (SEG / NT)     // 4 elements per thread == bits in the peak mask
#define NW (NT / 64)      // 16 waves
#define N_ITER 12
#define N_IMFS 6

#pragma clang fp contract(off)   // everything unfused EXCEPT the explicit fmaf

#define HSZS (SEG + (SEG >> 5))   // swizzled segment size (4224 floats)
__device__ __forceinline__ int physi(int i) { return i + (i >> 5); }

#define FMAXV 3.402823466e38f

// device-scope accessors for cross-block (cross-XCD) workspace slots
__device__ __forceinline__ void gstore(float* p, float v) {
  __hip_atomic_store(p, v, __ATOMIC_RELAXED, __HIP_MEMORY_SCOPE_AGENT);
}
__device__ __forceinline__ float gload(float* p) {
  return __hip_atomic_load(p, __ATOMIC_RELAXED, __HIP_MEMORY_SCOPE_AGENT);
}

// R17: row-split across 4 blocks -> 256 blocks = all CUs (was 64/256).
// R6 (231us) left VALUBusy at 42% on the 64 active CUs; the last 4x is CU
// count. sd/flat decisions were already grid-global with a grid barrier per
// iteration; the split adds only the within-row carry exchange:
//  - per block publish {last/first peak idx+val, rmx/rmn, counts} + h
//    boundaries to ws (device-scope stores; per-XCD L2 not coherent)
//  - per-row barrier (4 atomics on padded line), lane-parallel fetch
//  - t0 seeds the existing wave-carry chains with the cross-block carry
// All combines are max/min/int-sum (order-exact); published values are the
// same h floats previously read from LDS -> envelope math bit-identical.
// f64 atomicAdd grouping changes (256 vs 64 partials) - decision-robust as
// before. 64-VGPR discipline kept: streaming float4, no private arrays.
__global__ __launch_bounds__(NT, 4) void emd_main(
    const float* __restrict__ x, float* __restrict__ out, char* __restrict__ ws) {
  // ---- workspace layout ----
  unsigned* cnt    = (unsigned*)ws;              // [0] global barrier counter
  double*   sdsl   = (double*)(ws + 256);        // 6*12*2 doubles
  double*   flsl   = (double*)(ws + 1408);       // 6*4 doubles
  unsigned* rowcnt = (unsigned*)(ws + 2048);     // 64 counters, stride 16 uints
  float*    hbg    = (float*)(ws + 6144);        // HB[2][256][2] h boundaries
  float*    bsm    = (float*)(ws + 10240);       // BSUM[256][16]
  float*    rsb    = (float*)(ws + 26624);       // RESB[256] res first-elem

  __shared__ float hbuf[2 * HSZS];               // 33792 B double-buffered h
  __shared__ int wLU[NW], wLL[NW], wNU[NW], wNL[NW];
  __shared__ float wMx[NW], wMn[NW];
  __shared__ unsigned wCT[NW];
  __shared__ int eLU[NW], eLL[NW], eNU[NW], eNL[NW];
  __shared__ float eLUv[NW], eLLv[NW], eNUv[NW], eNLv[NW];
  __shared__ float eMx[NW], eMn[NW];
  __shared__ float bsl[12];        // own block summary staging
  __shared__ float nbs[NSEG][12];  // fetched row summaries
  __shared__ unsigned sTot;
  __shared__ float sBMx, sBMn;
  __shared__ double tA[NW], tB[NW], tC[NW], tD[NW];
  __shared__ int sFlag;

  const int t = threadIdx.x;
  const int lane = t & 63;
  const int wv = t >> 6;
  const int bid = blockIdx.x;
  const int row = bid >> 2;
  const int seg = bid & 3;
  const int seg0 = seg * SEG;
  const int seg1 = seg0 + SEG;
  const int bl = t * NC;        // local base in segment
  const int bg = seg0 + bl;     // global base in row
  const float* xr = x + (size_t)row * NL;
  float* res = out + (size_t)N_IMFS * NB * NL + (size_t)row * NL;

  int off = 0;      // current h buffer (0 or HSZS), globally uniform
  int hb = 0;       // current HB slot (0/1), globally uniform
  unsigned ep = 0;  // global barrier epoch
  unsigned rep = 0; // row barrier epoch

  // ---- init: h = x segment; res = x; publish boundaries ----
  {
    float4 v = *(const float4*)&xr[bg];
    *(float4*)&hbuf[physi(bl)] = v;
    *(float4*)&res[bg] = v;
    if (t == 0) { gstore(&hbg[(0 * 256 + bid) * 2 + 0], v.x); gstore(&rsb[bid], v.x); }
    if (t == NT - 1) gstore(&hbg[(0 * 256 + bid) * 2 + 1], v.w);
  }
  __syncthreads();
  rep++;
  if (t == 0) {   // row barrier: neighbors' boundary slots visible before iter 0
    __hip_atomic_fetch_add(&rowcnt[row * 16], 1u, __ATOMIC_ACQ_REL, __HIP_MEMORY_SCOPE_AGENT);
    while (__hip_atomic_load(&rowcnt[row * 16], __ATOMIC_ACQUIRE, __HIP_MEMORY_SCOPE_AGENT) < rep * NSEG)
      __builtin_amdgcn_s_sleep(1);
  }
  __syncthreads();

  bool done = false;

  for (int k = 0; k < N_IMFS; k++) {
    float* outk = out + (size_t)k * NB * NL + (size_t)row * NL;
    if (done) {  // globally-uniform skip (no barriers)
      *(float4*)&outk[bg] = make_float4(0.f, 0.f, 0.f, 0.f);
      continue;
    }

    // ---------------- sifting ----------------
    for (int it = 0; it < N_ITER; it++) {
      float* hcur = hbuf + off;
      float* hnx  = hbuf + (off ^ HSZS);

      // ---- pass A: peak masks + summaries (boundaries via HB slots) ----
      unsigned mU = 0, mL = 0;
      int lmU = -1, lmL = -1, cU = 0, cL = 0;
      float rmx = -FMAXV, rmn = FMAXV;
      {
        float hbPrev = 0.0f, hbNext = 0.0f;
        if (bl == 0 && bg > 0)
          hbPrev = gload(&hbg[(hb * 256 + bid - 1) * 2 + 1]);
        if (bl + NC == SEG && bg + NC < NL)
          hbNext = gload(&hbg[(hb * 256 + bid + 1) * 2 + 0]);
        float hm = (bg > 0) ? ((bl > 0) ? hcur[physi(bl - 1)] : hbPrev) : 0.0f;
        float nextv = (bl + NC < SEG) ? hcur[physi(bl + NC)] : hbNext;
        float4 cur = *(const float4*)&hcur[physi(bl)];
        #define PKSTEP(J, HC, HP) { int i = bg + (J);                         \
          bool in = (i > 0) && (i + 1 < NL);                                  \
          if (in && hm < (HC) && (HC) > (HP)) { mU |= 1u << (J); lmU = i; cU++; } \
          if (in && hm > (HC) && (HC) < (HP)) { mL |= 1u << (J); lmL = i; cL++; } \
          rmx = fmaxf(rmx, (HC)); rmn = fminf(rmn, (HC)); hm = (HC); }
        PKSTEP(0, cur.x, cur.y)
        PKSTEP(1, cur.y, cur.z)
        PKSTEP(2, cur.z, cur.w)
        PKSTEP(3, cur.w, nextv)
        #undef PKSTEP
      }
      int fpU = mU ? (bg + __ffs(mU) - 1) : NL;   // first own peak
      int fpL = mL ? (bg + __ffs(mL) - 1) : NL;
      unsigned long long bUm = __ballot(mU != 0);
      unsigned long long bLm = __ballot(mL != 0);
      // wave summaries: owning lane stores directly
      {
        int s;
        s = bUm ? (63 - __clzll((long long)bUm)) : 0;
        if (lane == s) wLU[wv] = bUm ? lmU : -1;
        s = bLm ? (63 - __clzll((long long)bLm)) : 0;
        if (lane == s) wLL[wv] = bLm ? lmL : -1;
        s = bUm ? (__ffsll(bUm) - 1) : 0;
        if (lane == s) wNU[wv] = bUm ? fpU : NL;
        s = bLm ? (__ffsll(bLm) - 1) : 0;
        if (lane == s) wNL[wv] = bLm ? fpL : NL;
      }
      // merged wave reduce: counts + wave max/min (for BSUM publish)
      unsigned ict = ((unsigned)cU << 16) | (unsigned)cL;
      {
        float wmx = rmx, wmn = rmn;
        #pragma unroll
        for (int o = 1; o < 64; o <<= 1) {
          unsigned cc = __shfl_down(ict, o, 64);
          float fa = __shfl_down(wmx, o, 64);
          float fb = __shfl_down(wmn, o, 64);
          if (lane + o < 64) { ict += cc; wmx = fmaxf(wmx, fa); wmn = fminf(wmn, fb); }
        }
        if (lane == 0) { wCT[wv] = ict; wMx[wv] = wmx; wMn[wv] = wmn; }
      }
      __syncthreads();   // S1
      if (t == 0) {      // block aggregates -> bsl
        int aLU = -1, aLL = -1, aNU = NL, aNL = NL;
        float aMx = -FMAXV, aMn = FMAXV; unsigned tt = 0;
        for (int w = 0; w < NW; w++) {
          if (wLU[w] > aLU) aLU = wLU[w];
          if (wLL[w] > aLL) aLL = wLL[w];
          if (wNU[w] < aNU) aNU = wNU[w];
          if (wNL[w] < aNL) aNL = wNL[w];
          aMx = fmaxf(aMx, wMx[w]); aMn = fminf(aMn, wMn[w]);
          tt += wCT[w];
        }
        bsl[0] = __int_as_float(aLU);
        bsl[1] = (aLU >= 0) ? hcur[physi(aLU - seg0)] : 0.0f;
        bsl[2] = __int_as_float(aLL);
        bsl[3] = (aLL >= 0) ? hcur[physi(aLL - seg0)] : 0.0f;
        bsl[4] = __int_as_float(aNU);
        bsl[5] = (aNU < NL) ? hcur[physi(aNU - seg0)] : 0.0f;
        bsl[6] = __int_as_float(aNL);
        bsl[7] = (aNL < NL) ? hcur[physi(aNL - seg0)] : 0.0f;
        bsl[8] = aMx; bsl[9] = aMn;
        bsl[10] = __uint_as_float(tt);
        bsl[11] = 0.f;
      }
      __syncthreads();   // S2
      rep++;
      if (wv == 0) {     // publish + row barrier + fetch (lane-parallel)
        if (lane < 12) gstore(&bsm[bid * 16 + lane], bsl[lane]);
        if (lane == 0) {
          __hip_atomic_fetch_add(&rowcnt[row * 16], 1u, __ATOMIC_ACQ_REL, __HIP_MEMORY_SCOPE_AGENT);
          while (__hip_atomic_load(&rowcnt[row * 16], __ATOMIC_ACQUIRE, __HIP_MEMORY_SCOPE_AGENT) < rep * NSEG)
            __builtin_amdgcn_s_sleep(1);
        }
        if (lane < 48) {
          int s = lane / 12, sl = lane % 12;
          nbs[s][sl] = gload(&bsm[(row * 4 + s) * 16 + sl]);
        }
      }
      __syncthreads();   // S3
      if (t == 0) {      // cross-block combine + seeded exclusive wave chains
        int bclU = -1, bclL = -1; float bclUv = 0.f, bclLv = 0.f;
        float bMx = -FMAXV, bMn = FMAXV;
        for (int s = 0; s < seg; s++) {
          int v = __float_as_int(nbs[s][0]);
          if (v > bclU) { bclU = v; bclUv = nbs[s][1]; }
          v = __float_as_int(nbs[s][2]);
          if (v > bclL) { bclL = v; bclLv = nbs[s][3]; }
          bMx = fmaxf(bMx, nbs[s][8]);
          bMn = fminf(bMn, nbs[s][9]);
        }
        int bcnU = NL, bcnL = NL; float bcnUv = 0.f, bcnLv = 0.f;
        for (int s = NSEG - 1; s > seg; s--) {
          int v = __float_as_int(nbs[s][4]);
          if (v < bcnU) { bcnU = v; bcnUv = nbs[s][5]; }
          v = __float_as_int(nbs[s][6]);
          if (v < bcnL) { bcnL = v; bcnLv = nbs[s][7]; }
        }
        unsigned tot = 0;
        for (int s = 0; s < NSEG; s++) tot += __float_as_uint(nbs[s][10]);
        sTot = tot; sBMx = bMx; sBMn = bMn;
        int aLU = bclU, aLL = bclL; float aLUv = bclUv, aLLv = bclLv;
        for (int w = 0; w < NW; w++) {
          eLU[w] = aLU; eLUv[w] = aLUv; eLL[w] = aLL; eLLv[w] = aLLv;
          if (wLU[w] > aLU) { aLU = wLU[w]; aLUv = hcur[physi(aLU - seg0)]; }
          if (wLL[w] > aLL) { aLL = wLL[w]; aLLv = hcur[physi(aLL - seg0)]; }
        }
        int aNU = bcnU, aNL2 = bcnL; float aNUv = bcnUv, aNLv = bcnLv;
        for (int w = NW - 1; w >= 0; w--) {
          eNU[w] = aNU; eNUv[w] = aNUv; eNL[w] = aNL2; eNLv[w] = aNLv;
          if (wNU[w] < aNU) { aNU = wNU[w]; aNUv = hcur[physi(aNU - seg0)]; }
          if (wNL[w] < aNL2) { aNL2 = wNL[w]; aNLv = hcur[physi(aNL2 - seg0)]; }
        }
      }
      __syncthreads();   // S4
      const unsigned tot = sTot;
      const int totU = (int)(tot >> 16), totL = (int)(tot & 0xffffu);

      // per-thread carries: ballot bit-ops + one dynamic shuffle each
      unsigned long long belowU = bUm & ((1ull << lane) - 1ull);
      unsigned long long belowL = bLm & ((1ull << lane) - 1ull);
      unsigned long long aboveU = (lane == 63) ? 0ull : (bUm & (~0ull << (lane + 1)));
      unsigned long long aboveL = (lane == 63) ? 0ull : (bLm & (~0ull << (lane + 1)));
      int slU = belowU ? (63 - __clzll((long long)belowU)) : 0;
      int slL = belowL ? (63 - __clzll((long long)belowL)) : 0;
      int snU = aboveU ? (__ffsll(aboveU) - 1) : 0;
      int snL = aboveL ? (__ffsll(aboveL) - 1) : 0;
      int gU  = __shfl(lmU, slU, 64);
      int gL  = __shfl(lmL, slL, 64);
      int gNU = __shfl(fpU, snU, 64);
      int gNL = __shfl(fpL, snL, 64);
      const int clU = belowU ? gU  : eLU[wv];
      const int clL = belowL ? gL  : eLL[wv];
      const int cnU = aboveU ? gNU : eNU[wv];
      const int cnL = aboveL ? gNL : eNL[wv];
      const float cnUv = eNUv[wv];   // valid when cnU >= seg1 (incl. NL)
      const float cnLv = eNLv[wv];
      float vl0 = belowU ? hcur[physi(gU - seg0)] : ((clU >= 0) ? eLUv[wv] : 0.0f);
      float wl0 = belowL ? hcur[physi(gL - seg0)] : ((clL >= 0) ? eLLv[wv] : 0.0f);

      // Mx/Mn prefix carries only for the rare <2-peaks fallback (row-uniform)
      float crx = -FMAXV, crn = FMAXV;
      if (totU < 2 || totL < 2) {
        float iMx = rmx, iMn = rmn;
        #pragma unroll
        for (int o = 1; o < 64; o <<= 1) {
          float fa = __shfl_up(iMx, o, 64);
          float fb = __shfl_up(iMn, o, 64);
          if (lane >= o) { iMx = fmaxf(iMx, fa); iMn = fminf(iMn, fb); }
        }
        if (lane == 63) { wMx[wv] = iMx; wMn[wv] = iMn; }
        __syncthreads();
        if (t == 0) {
          float aMx = sBMx, aMn = sBMn;   // seeded with cross-block carry
          for (int w = 0; w < NW; w++) {
            eMx[w] = aMx; aMx = fmaxf(aMx, wMx[w]);
            eMn[w] = aMn; aMn = fminf(aMn, wMn[w]);
          }
        }
        __syncthreads();
        float pMx = __shfl_up(iMx, 1, 64); if (lane == 0) pMx = -FMAXV;
        float pMn = __shfl_up(iMn, 1, 64); if (lane == 0) pMn = FMAXV;
        crx = fmaxf(eMx[wv], pMx);
        crn = fminf(eMn[wv], pMn);
      }

      // ---- pass C: envelopes + mean (frozen f32 ladder); h_next -> hnx ----
      double pm2 = 0.0, ph2 = 0.0;
      {
        float rx = crx, rn = crn;
        int curLU = clU, curLL = clL;
        float vl = vl0, wl = wl0;
        int gB = -0x7fffffff, gD = -0x7fffffff;
        float vr = 0.0f, wr = 0.0f;
        #define ENVSTEP(J, HC, OD) { int i = bg + (J); float hc = (HC);       \
          rx = fmaxf(rx, hc); rn = fminf(rn, hc);                             \
          if ((mU >> (J)) & 1u) { curLU = i; vl = hc; }                       \
          if ((mL >> (J)) & 1u) { curLL = i; wl = hc; }                       \
          int lU = curLU, lL = curLL;                                         \
          unsigned highm = 0xFFFFFFFFu << (J); unsigned a;                    \
          a = mU & highm; int nUv = a ? (bg + __ffs(a) - 1) : cnU;            \
          a = mL & highm; int nLv = a ? (bg + __ffs(a) - 1) : cnL;            \
          if (nUv != gB) { gB = nUv;                                          \
            vr = (nUv < seg1) ? hcur[physi(nUv - seg0)] : cnUv; }             \
          if (nLv != gD) { gD = nLv;                                          \
            wr = (nLv < seg1) ? hcur[physi(nLv - seg0)] : cnLv; }             \
          int den = nUv - lU;                                                 \
          float fracU = (float)(i - lU) / (float)(den > 0 ? den : 1);         \
          float envU = (den > 0) ? __builtin_fmaf(fracU, vr - vl, vl) : vl;   \
          if (lU < 0) envU = vr;                                              \
          if (nUv >= NL) envU = vl;                                           \
          if (totU < 2) envU = rx;                                            \
          int den2 = nLv - lL;                                                \
          float fracL = (float)(i - lL) / (float)(den2 > 0 ? den2 : 1);       \
          float envL = (den2 > 0) ? __builtin_fmaf(fracL, wr - wl, wl) : wl;  \
          if (lL < 0) envL = wr;                                              \
          if (nLv >= NL) envL = wl;                                           \
          if (totL < 2) envL = rn;                                            \
          float mn = 0.5f * (envU + envL);                                    \
          (OD) = hc - mn;                                                     \
          pm2 += (double)mn * (double)mn; ph2 += (double)hc * (double)hc; }
        float4 hv4 = *(const float4*)&hcur[physi(bl)];
        float4 o4;
        ENVSTEP(0, hv4.x, o4.x)
        ENVSTEP(1, hv4.y, o4.y)
        ENVSTEP(2, hv4.z, o4.z)
        ENVSTEP(3, hv4.w, o4.w)
        #undef ENVSTEP
        *(float4*)&hnx[physi(bl)] = o4;
        int nhb = hb ^ 1;   // publish h_next boundaries
        if (t == 0)      gstore(&hbg[(nhb * 256 + bid) * 2 + 0], o4.x);
        if (t == NT - 1) gstore(&hbg[(nhb * 256 + bid) * 2 + 1], o4.w);
      }
      // block reduction of (pm2, ph2)
      #pragma unroll
      for (int o = 1; o < 64; o <<= 1) {
        double a = __shfl_down(pm2, o, 64);
        double b = __shfl_down(ph2, o, 64);
        if (lane + o < 64) { pm2 += a; ph2 += b; }
      }
      if (lane == 0) { tA[wv] = pm2; tB[wv] = ph2; }
      // ---- grid barrier + convergence decision ----
      ep++;
      __syncthreads();   // S5: orders tA/tB, hnx, hbg publishes
      if (t == 0) {
        double sA = 0.0, sB = 0.0;
        for (int w = 0; w < NW; w++) { sA += tA[w]; sB += tB[w]; }
        atomicAdd(&sdsl[(k * N_ITER + it) * 2 + 0], sA);
        atomicAdd(&sdsl[(k * N_ITER + it) * 2 + 1], sB);
        __hip_atomic_fetch_add(cnt, 1u, __ATOMIC_ACQ_REL, __HIP_MEMORY_SCOPE_AGENT);
        unsigned tgt = ep * gridDim.x;
        while (__hip_atomic_load(cnt, __ATOMIC_ACQUIRE, __HIP_MEMORY_SCOPE_AGENT) < tgt)
          __builtin_amdgcn_s_sleep(1);
        double m2 = __hip_atomic_load(&sdsl[(k * N_ITER + it) * 2 + 0],
                                      __ATOMIC_RELAXED, __HIP_MEMORY_SCOPE_AGENT);
        double h2 = __hip_atomic_load(&sdsl[(k * N_ITER + it) * 2 + 1],
                                      __ATOMIC_RELAXED, __HIP_MEMORY_SCOPE_AGENT);
        sFlag = (m2 / (h2 + 1e-8) < 0.05) ? 1 : 0;
      }
      __syncthreads();   // S6
      if (sFlag) break;   // converged: keep OLD buffer (h frozen, JAX latch)
      off ^= HSZS; hb ^= 1;
    }

    // ------------- flatness test + outputs (f32 values, f64 sums) -------------
    float* hcur = hbuf + off;
    double s1 = 0.0, s2 = 0.0, s3 = 0.0, s4 = 0.0;
    {
      float rbv = 0.0f;   // res-h at bg+NC (next thread / next block)
      if (bg + NC < NL) {
        float rnext = (bl + NC < SEG) ? res[bg + NC] : gload(&rsb[bid + 1]);
        float hnext = (bl + NC < SEG) ? hcur[physi(bl + NC)]
                                      : gload(&hbg[(hb * 256 + bid + 1) * 2 + 0]);
        rbv = rnext - hnext;
      }
      float4 rv4 = *(const float4*)&res[bg];
      float4 hv4 = *(const float4*)&hcur[physi(bl)];
      float e0 = rv4.x - hv4.x, e1 = rv4.y - hv4.y,
            e2 = rv4.z - hv4.z, e3 = rv4.w - hv4.w;
      #define FLSTEP(J, CUR, NXT) { int i = bg + (J);                         \
        s1 += (double)(CUR); s2 += (double)(CUR) * (double)(CUR);             \
        if (i + 1 < NL) { float dd = (NXT) - (CUR);                           \
          s3 += (double)dd; s4 += (double)dd * (double)dd; } }
      FLSTEP(0, e0, e1)
      FLSTEP(1, e1, e2)
      FLSTEP(2, e2, e3)
      FLSTEP(3, e3, rbv)
      #undef FLSTEP
    }
    #pragma unroll
    for (int o = 1; o < 64; o <<= 1) {
      double a = __shfl_down(s1, o, 64);
      double b = __shfl_down(s2, o, 64);
      double c = __shfl_down(s3, o, 64);
      double d = __shfl_down(s4, o, 64);
      if (lane + o < 64) { s1 += a; s2 += b; s3 += c; s4 += d; }
    }
    if (lane == 0) { tA[wv] = s1; tB[wv] = s2; tC[wv] = s3; tD[wv] = s4; }
    __syncthreads();
    if (t == 0) {
      double S1 = 0.0, S2 = 0.0, S3 = 0.0, S4 = 0.0;
      for (int w = 0; w < NW; w++) { S1 += tA[w]; S2 += tB[w]; S3 += tC[w]; S4 += tD[w]; }
      atomicAdd(&flsl[k * 4 + 0], S1);
      atomicAdd(&flsl[k * 4 + 1], S2);
      atomicAdd(&flsl[k * 4 + 2], S3);
      atomicAdd(&flsl[k * 4 + 3], S4);
    }
    // outputs: IMF k = h; res -= h; h <- new res; publish boundaries
    {
      float4 rv4 = *(const float4*)&res[bg];
      float4 hv4 = *(const float4*)&hcur[physi(bl)];
      float4 rq = make_float4(rv4.x - hv4.x, rv4.y - hv4.y,
                              rv4.z - hv4.z, rv4.w - hv4.w);
      *(float4*)&outk[bg] = hv4;
      *(float4*)&res[bg] = rq;
      *(float4*)&hcur[physi(bl)] = rq;
      if (t == 0) {
        gstore(&hbg[(hb * 256 + bid) * 2 + 0], rq.x);
        gstore(&rsb[bid], rq.x);
      }
      if (t == NT - 1) gstore(&hbg[(hb * 256 + bid) * 2 + 1], rq.w);
    }
    // ---- grid barrier + flatness decision ----
    ep++;
    __syncthreads();
    if (t == 0) {
      __hip_atomic_fetch_add(cnt, 1u, __ATOMIC_ACQ_REL, __HIP_MEMORY_SCOPE_AGENT);
      unsigned tgt = ep * gridDim.x;
      while (__hip_atomic_load(cnt, __ATOMIC_ACQUIRE, __HIP_MEMORY_SCOPE_AGENT) < tgt)
        __builtin_amdgcn_s_sleep(1);
      double S1 = __hip_atomic_load(&flsl[k * 4 + 0], __ATOMIC_RELAXED, __HIP_MEMORY_SCOPE_AGENT);
      double S2 = __hip_atomic_load(&flsl[k * 4 + 1], __ATOMIC_RELAXED, __HIP_MEMORY_SCOPE_AGENT);
      double S3 = __hip_atomic_load(&flsl[k * 4 + 2], __ATOMIC_RELAXED, __HIP_MEMORY_SCOPE_AGENT);
      double S4 = __hip_atomic_load(&flsl[k * 4 + 3], __ATOMIC_RELAXED, __HIP_MEMORY_SCOPE_AGENT);
      double nr = (double)NB * (double)NL;
      double nd = (double)NB * (double)(NL - 1);
      double varr = (S2 - S1 * S1 / nr) / (nr - 1.0);
      double vard = (S4 - S3 * S3 / nd) / (nd - 1.0);
      sFlag = (vard < 0.05 * varr) ? 1 : 0;
    }
    __syncthreads();
    done = done || (sFlag != 0);
  }
}

extern "C" void kernel_launch(void* const* d_in, const int* in_sizes, int n_in,
                              void* d_out, int out_size, void* d_ws, size_t ws_size,
                              hipStream_t stream) {
  const float* x = (const float*)d_in[0];
  float* out = (float*)d_out;
  // ws: [0] cnt; [256] sd slots; [1408] flat slots; [2048] row counters;
  //     [6144] HB; [10240] BSUM; [26624] RESB  (needs ~27.6KB)
  size_t zb = ws_size < 6144 ? ws_size : 6144;   // zero counters + sums only
  hipMemsetAsync(d_ws, 0, zb, stream);
  hipLaunchKernelGGL(emd_main, dim3(NB * NSEG), dim3(NT), 0, stream,
                     x, out, (char*)d_ws);
}

// Round 8
// 330.587 us; speedup vs baseline: 1.3554x; 1.3554x over previous
//
#include <hip/hip_runtime.h>

#define NL 16384          // row length
#define NB 64             // rows = blocks
#define NT 1024           // threads per block (16 waves = 4 waves/SIMD)
#define NC (NL / NT)      // 16 elements per thread == bits in the peak mask
#define NW (NT / 64)      // 16 waves
#define N_ITER 12
#define N_IMFS 6

#pragma clang fp contract(off)   // everything unfused EXCEPT the explicit fmaf

#define HSZ (NL + (NL >> 5))   // +1 float per 32: 2-way-max banking (free)
__device__ __forceinline__ int physi(int i) { return i + (i >> 5); }

#define FMAXV 3.402823466e38f

// Frozen bit-exact semantics (certified R9/R11 + R6 structure, absmax 0.0).
// R6 (231us): DS-diet + dbuf h, 64 blocks, 1 grid barrier per sift iter.
// R7 (388us): row-split got 48% occupancy but added a 2nd device barrier per
// iter -> per-CU VALUBusy fell to 9.7%. Arithmetic: each exposed device
// barrier ~2us; R6 runs ~78 -> ~150us of R6's 231 is barrier EXPOSURE.
// R18: lag-1 convergence protocol on the R6 structure. With dbuf h, a block
// only needs conv_{it-1} resolved before iteration it overwrites s_{it-1}'s
// buffer. So: post sd partials + arrival counter (NO wait), resolve
// conv_{it-1} at the next iteration's top -- posted a full iteration ago by
// all blocks, so the poll completes without spinning. First true conv found
// in order; final h = s_{it-1} still in the other buffer (flip back). Only
// exposed wait: conv_11 once per IMF. Flatness decision resolved with a
// full-IMF lag (done_{k-1} at IMF k's output phase). Decision values and the
// entire f32 value ladder identical to R6.
__global__ __launch_bounds__(NT, 4) void emd_main(
    const float* __restrict__ x, float* __restrict__ out, char* __restrict__ ws) {
  // ---- workspace: lag-resolved decision slots (all zeroed by host) ----
  unsigned* scnt = (unsigned*)ws;           // [72] sd slot arrival counters
  double*   sdsl = (double*)(ws + 512);     // [72][2] {sum mean^2, sum h^2}
  unsigned* fcnt = (unsigned*)(ws + 2048);  // [6] flat slot arrival counters
  double*   flsl = (double*)(ws + 2304);    // [6][4] {S1,S2,S3,S4}

  __shared__ float hbuf[2 * HSZ];   // 135168 B double-buffered h
  __shared__ int wLU[NW], wLL[NW], wNU[NW], wNL[NW];
  __shared__ float wMx[NW], wMn[NW];
  __shared__ unsigned wCT[NW];
  __shared__ int eLU[NW], eLL[NW], eNU[NW], eNL[NW];
  __shared__ float eMx[NW], eMn[NW];
  __shared__ unsigned sTot;
  __shared__ double tA[NW], tB[NW], tC[NW], tD[NW];
  __shared__ int sFlag;

  const int t = threadIdx.x;
  const int lane = t & 63;
  const int wv = t >> 6;
  const int row = blockIdx.x;
  const int base = t * NC;
  const float* xr = x + (size_t)row * NL;
  float* res = out + (size_t)N_IMFS * NB * NL + (size_t)row * NL;

  int off = 0;   // current h buffer offset (0 or HSZ), globally uniform

  // init: h = x row (LDS, swizzled); res slab of d_out = x
  #pragma unroll
  for (int q = 0; q < NC / 4; q++) {
    int i0 = base + q * 4;
    float4 v = *(const float4*)&xr[i0];
    *(float4*)&hbuf[physi(i0)] = v;
    *(float4*)&res[i0] = v;
  }
  __syncthreads();

  bool done = false;

  for (int k = 0; k < N_IMFS; k++) {
    float* outk = out + (size_t)k * NB * NL + (size_t)row * NL;
    if (done) {  // resolved-done skip (uniform, no barriers, no posts)
      #pragma unroll
      for (int q = 0; q < NC / 4; q++)
        *(float4*)&outk[base + q * 4] = make_float4(0.f, 0.f, 0.f, 0.f);
      continue;
    }

    // ---------------- sifting (lag-1 convergence) ----------------
    int fin = 0;
    for (int it = 0; it < N_ITER; it++) {
      // resolve conv_{it-1}: posted one full iteration ago -> no spin expected
      if (it >= 1) {
        if (t == 0) {
          int s = k * N_ITER + (it - 1);
          while (__hip_atomic_load(&scnt[s], __ATOMIC_ACQUIRE, __HIP_MEMORY_SCOPE_AGENT) < NB)
            __builtin_amdgcn_s_sleep(1);
          double m2 = __hip_atomic_load(&sdsl[s * 2 + 0], __ATOMIC_RELAXED, __HIP_MEMORY_SCOPE_AGENT);
          double h2 = __hip_atomic_load(&sdsl[s * 2 + 1], __ATOMIC_RELAXED, __HIP_MEMORY_SCOPE_AGENT);
          sFlag = (m2 / (h2 + 1e-8) < 0.05) ? 1 : 0;
        }
        __syncthreads();   // broadcast + orders prev pass C writes for pass A
        if (sFlag) { off ^= HSZ; fin = 1; break; }   // final = s_{it-1}
      }
      float* hcur = hbuf + off;
      float* hnx  = hbuf + (off ^ HSZ);

      // pass A: chunked rolling walk -> peak masks + chunk summaries
      unsigned mU = 0, mL = 0;
      int lmU = -1, lmL = -1, cU = 0, cL = 0;
      float rmx = -FMAXV, rmn = FMAXV;
      {
        float hm = (base > 0) ? hcur[physi(base - 1)] : 0.0f;
        float4 cur = *(const float4*)&hcur[physi(base)];
        #define PKSTEP(J, HC, HP) { int i = base + (J);                     \
          bool in = (i > 0) && (i + 1 < NL);                                \
          if (in && hm < (HC) && (HC) > (HP)) { mU |= 1u << (J); lmU = i; cU++; } \
          if (in && hm > (HC) && (HC) < (HP)) { mL |= 1u << (J); lmL = i; cL++; } \
          rmx = fmaxf(rmx, (HC)); rmn = fminf(rmn, (HC)); hm = (HC); }
        #pragma unroll
        for (int q = 0; q < 4; q++) {
          float4 nxt = cur;
          float n0;
          if (q < 3) { nxt = *(const float4*)&hcur[physi(base + q * 4 + 4)]; n0 = nxt.x; }
          else       { n0 = (base + 16 < NL) ? hcur[physi(base + 16)] : 0.0f; }
          PKSTEP(q * 4 + 0, cur.x, cur.y)
          PKSTEP(q * 4 + 1, cur.y, cur.z)
          PKSTEP(q * 4 + 2, cur.z, cur.w)
          PKSTEP(q * 4 + 3, cur.w, n0)
          cur = nxt;
        }
        #undef PKSTEP
      }
      int fpU = mU ? (base + __ffs(mU) - 1) : NL;   // first own peak
      int fpL = mL ? (base + __ffs(mL) - 1) : NL;
      unsigned long long bUm = __ballot(mU != 0);
      unsigned long long bLm = __ballot(mL != 0);
      // wave summaries: owning lane stores directly (no scans)
      {
        int s;
        s = bUm ? (63 - __clzll((long long)bUm)) : 0;
        if (lane == s) wLU[wv] = bUm ? lmU : -1;
        s = bLm ? (63 - __clzll((long long)bLm)) : 0;
        if (lane == s) wLL[wv] = bLm ? lmL : -1;
        s = bUm ? (__ffsll(bUm) - 1) : 0;
        if (lane == s) wNU[wv] = bUm ? fpU : NL;
        s = bLm ? (__ffsll(bLm) - 1) : 0;
        if (lane == s) wNL[wv] = bLm ? fpL : NL;
      }
      // block peak-count totals (reduce only; same pairwise order as before)
      unsigned ict = ((unsigned)cU << 16) | (unsigned)cL;
      #pragma unroll
      for (int o = 1; o < 64; o <<= 1) {
        unsigned cc = __shfl_down(ict, o, 64);
        if (lane + o < 64) ict += cc;
      }
      if (lane == 0) wCT[wv] = ict;
      __syncthreads();   // S1
      if (t == 0) {      // 16-entry serial combine -> exclusive wave carries
        int aLU = -1, aLL = -1; unsigned tt = 0;
        for (int w = 0; w < NW; w++) {
          eLU[w] = aLU; aLU = max(aLU, wLU[w]);
          eLL[w] = aLL; aLL = max(aLL, wLL[w]);
          tt += wCT[w];
        }
        int aNU = NL, aNL = NL;
        for (int w = NW - 1; w >= 0; w--) {
          eNU[w] = aNU; aNU = min(aNU, wNU[w]);
          eNL[w] = aNL; aNL = min(aNL, wNL[w]);
        }
        sTot = tt;
      }
      __syncthreads();   // S2
      const unsigned tot = sTot;
      const int totU = (int)(tot >> 16), totL = (int)(tot & 0xffffu);

      // per-thread carries via ballot bit-ops + one dynamic shuffle each
      unsigned long long belowU = bUm & ((1ull << lane) - 1ull);
      unsigned long long belowL = bLm & ((1ull << lane) - 1ull);
      unsigned long long aboveU = (lane == 63) ? 0ull : (bUm & (~0ull << (lane + 1)));
      unsigned long long aboveL = (lane == 63) ? 0ull : (bLm & (~0ull << (lane + 1)));
      int slU = belowU ? (63 - __clzll((long long)belowU)) : 0;
      int slL = belowL ? (63 - __clzll((long long)belowL)) : 0;
      int snU = aboveU ? (__ffsll(aboveU) - 1) : 0;
      int snL = aboveL ? (__ffsll(aboveL) - 1) : 0;
      int gU  = __shfl(lmU, slU, 64);
      int gL  = __shfl(lmL, slL, 64);
      int gNU = __shfl(fpU, snU, 64);
      int gNL = __shfl(fpL, snL, 64);
      const int clU = belowU ? gU  : eLU[wv];
      const int clL = belowL ? gL  : eLL[wv];
      const int cnU = aboveU ? gNU : eNU[wv];
      const int cnL = aboveL ? gNL : eNL[wv];

      // Mx/Mn prefix carries only needed for the <2-peaks fallback (rare);
      // tot is block-uniform so the branch (and its barriers) is uniform.
      float crx = -FMAXV, crn = FMAXV;
      if (totU < 2 || totL < 2) {
        float iMx = rmx, iMn = rmn;
        #pragma unroll
        for (int o = 1; o < 64; o <<= 1) {
          float fa = __shfl_up(iMx, o, 64);
          float fb = __shfl_up(iMn, o, 64);
          if (lane >= o) { iMx = fmaxf(iMx, fa); iMn = fminf(iMn, fb); }
        }
        if (lane == 63) { wMx[wv] = iMx; wMn[wv] = iMn; }
        __syncthreads();
        if (t == 0) {
          float aMx = -FMAXV, aMn = FMAXV;
          for (int w = 0; w < NW; w++) {
            eMx[w] = aMx; aMx = fmaxf(aMx, wMx[w]);
            eMn[w] = aMn; aMn = fminf(aMn, wMn[w]);
          }
        }
        __syncthreads();
        float pMx = __shfl_up(iMx, 1, 64); if (lane == 0) pMx = -FMAXV;
        float pMn = __shfl_up(iMn, 1, 64); if (lane == 0) pMn = FMAXV;
        crx = fmaxf(eMx[wv], pMx);
        crn = fminf(eMn[wv], pMn);
      }

      // pass C: envelopes + mean (frozen f32 ladder), streaming b128 chunks;
      // h_next = hc - mn written inline to the other buffer (dbuf subtract).
      double pm2 = 0.0, ph2 = 0.0;
      {
        float rx = crx, rn = crn;
        int curLU = clU, curLL = clL;
        float vl = hcur[physi(clU < 0 ? 0 : clU)];   // carry-in gathers
        float wl = hcur[physi(clL < 0 ? 0 : clL)];
        int gB = -0x7fffffff, gD = -0x7fffffff;
        float vr = 0.0f, wr = 0.0f;
        #define ENVSTEP(J, HC, OD) { int i = base + (J); float hc = (HC);   \
          rx = fmaxf(rx, hc); rn = fminf(rn, hc);                           \
          if ((mU >> (J)) & 1u) { curLU = i; vl = hc; }                     \
          if ((mL >> (J)) & 1u) { curLL = i; wl = hc; }                     \
          int lU = curLU, lL = curLL;                                       \
          unsigned highm = 0xFFFFFFFFu << (J); unsigned a;                  \
          a = mU & highm; int nUv = a ? (base + __ffs(a) - 1) : cnU;        \
          a = mL & highm; int nLv = a ? (base + __ffs(a) - 1) : cnL;        \
          if (nUv != gB) { gB = nUv; vr = hcur[physi(nUv >= NL ? NL - 1 : nUv)]; } \
          if (nLv != gD) { gD = nLv; wr = hcur[physi(nLv >= NL ? NL - 1 : nLv)]; } \
          int den = nUv - lU;                                               \
          float fracU = (float)(i - lU) / (float)(den > 0 ? den : 1);       \
          float envU = (den > 0) ? __builtin_fmaf(fracU, vr - vl, vl) : vl; \
          if (lU < 0) envU = vr;                                            \
          if (nUv >= NL) envU = vl;                                         \
          if (totU < 2) envU = rx;                                          \
          int den2 = nLv - lL;                                              \
          float fracL = (float)(i - lL) / (float)(den2 > 0 ? den2 : 1);     \
          float envL = (den2 > 0) ? __builtin_fmaf(fracL, wr - wl, wl) : wl;\
          if (lL < 0) envL = wr;                                            \
          if (nLv >= NL) envL = wl;                                         \
          if (totL < 2) envL = rn;                                          \
          float mn = 0.5f * (envU + envL);                                  \
          (OD) = hc - mn;                                                   \
          pm2 += (double)mn * (double)mn; ph2 += (double)hc * (double)hc; }
        #pragma unroll
        for (int q = 0; q < 4; q++) {
          int i0 = base + q * 4;
          float4 hv4 = *(const float4*)&hcur[physi(i0)];
          float4 o4;
          ENVSTEP(q * 4 + 0, hv4.x, o4.x)
          ENVSTEP(q * 4 + 1, hv4.y, o4.y)
          ENVSTEP(q * 4 + 2, hv4.z, o4.z)
          ENVSTEP(q * 4 + 3, hv4.w, o4.w)
          *(float4*)&hnx[physi(i0)] = o4;
        }
        #undef ENVSTEP
      }
      // fused block reduction of (pm2, ph2)
      #pragma unroll
      for (int o = 1; o < 64; o <<= 1) {
        double a = __shfl_down(pm2, o, 64);
        double b = __shfl_down(ph2, o, 64);
        if (lane + o < 64) { pm2 += a; ph2 += b; }
      }
      if (lane == 0) { tA[wv] = pm2; tB[wv] = ph2; }
      __syncthreads();   // S5: orders tA/tB and hnx writes
      if (t == 0) {      // post partials + arrival -- NO WAIT (lag-1)
        double sA = 0.0, sB = 0.0;
        for (int w = 0; w < NW; w++) { sA += tA[w]; sB += tB[w]; }
        int s = k * N_ITER + it;
        atomicAdd(&sdsl[s * 2 + 0], sA);
        atomicAdd(&sdsl[s * 2 + 1], sB);
        __hip_atomic_fetch_add(&scnt[s], 1u, __ATOMIC_ACQ_REL, __HIP_MEMORY_SCOPE_AGENT);
      }
      off ^= HSZ;        // accept h_next provisionally (revocable via lag)
    }
    if (!fin) {          // ran all 12: resolve conv_11 (the one exposed wait)
      if (t == 0) {
        int s = k * N_ITER + (N_ITER - 1);
        while (__hip_atomic_load(&scnt[s], __ATOMIC_ACQUIRE, __HIP_MEMORY_SCOPE_AGENT) < NB)
          __builtin_amdgcn_s_sleep(1);
        double m2 = __hip_atomic_load(&sdsl[s * 2 + 0], __ATOMIC_RELAXED, __HIP_MEMORY_SCOPE_AGENT);
        double h2 = __hip_atomic_load(&sdsl[s * 2 + 1], __ATOMIC_RELAXED, __HIP_MEMORY_SCOPE_AGENT);
        sFlag = (m2 / (h2 + 1e-8) < 0.05) ? 1 : 0;
      }
      __syncthreads();
      if (sFlag) off ^= HSZ;   // final = s_11
    }

    float* hcur = hbuf + off;  // h_final

    // ---- resolve done_{k-1}: flat posted a full IMF ago -> no spin ----
    if (k > 0) {
      if (t == 0) {
        while (__hip_atomic_load(&fcnt[k - 1], __ATOMIC_ACQUIRE, __HIP_MEMORY_SCOPE_AGENT) < NB)
          __builtin_amdgcn_s_sleep(1);
        double S1 = __hip_atomic_load(&flsl[(k - 1) * 4 + 0], __ATOMIC_RELAXED, __HIP_MEMORY_SCOPE_AGENT);
        double S2 = __hip_atomic_load(&flsl[(k - 1) * 4 + 1], __ATOMIC_RELAXED, __HIP_MEMORY_SCOPE_AGENT);
        double S3 = __hip_atomic_load(&flsl[(k - 1) * 4 + 2], __ATOMIC_RELAXED, __HIP_MEMORY_SCOPE_AGENT);
        double S4 = __hip_atomic_load(&flsl[(k - 1) * 4 + 3], __ATOMIC_RELAXED, __HIP_MEMORY_SCOPE_AGENT);
        double nr = (double)NB * (double)NL;
        double nd = (double)NB * (double)(NL - 1);
        double varr = (S2 - S1 * S1 / nr) / (nr - 1.0);
        double vard = (S4 - S3 * S3 / nd) / (nd - 1.0);
        sFlag = (vard < 0.05 * varr) ? 1 : 0;
      }
      __syncthreads();
      if (sFlag) done = true;
    }
    if (done) {  // flat at k-1: this IMF's sifting is discarded (ref: zeros)
      #pragma unroll
      for (int q = 0; q < NC / 4; q++)
        *(float4*)&outk[base + q * 4] = make_float4(0.f, 0.f, 0.f, 0.f);
      continue;
    }

    // ------------- flatness partials (f32 values, f64 sums) -------------
    double s1 = 0.0, s2 = 0.0, s3 = 0.0, s4 = 0.0;
    {
      float rb = 0.0f;   // res-h at base+NC (next thread's first element)
      if (base + NC < NL) rb = res[base + NC] - hcur[physi(base + NC)];
      float4 rv4 = *(const float4*)&res[base];
      float4 hv4 = *(const float4*)&hcur[physi(base)];
      float e0 = rv4.x - hv4.x, e1 = rv4.y - hv4.y,
            e2 = rv4.z - hv4.z, e3 = rv4.w - hv4.w;
      #define FLSTEP(J, CUR, NXT) { int i = base + (J);                     \
        s1 += (double)(CUR); s2 += (double)(CUR) * (double)(CUR);           \
        if (i + 1 < NL) { float dd = (NXT) - (CUR);                         \
          s3 += (double)dd; s4 += (double)dd * (double)dd; } }
      #pragma unroll
      for (int q = 0; q < 4; q++) {
        float c0 = e0, c1 = e1, c2 = e2, c3 = e3;
        float n0;
        if (q < 3) {
          int i0 = base + q * 4 + 4;
          rv4 = *(const float4*)&res[i0];
          hv4 = *(const float4*)&hcur[physi(i0)];
          e0 = rv4.x - hv4.x; e1 = rv4.y - hv4.y;
          e2 = rv4.z - hv4.z; e3 = rv4.w - hv4.w;
          n0 = e0;
        } else n0 = rb;
        FLSTEP(q * 4 + 0, c0, c1)
        FLSTEP(q * 4 + 1, c1, c2)
        FLSTEP(q * 4 + 2, c2, c3)
        FLSTEP(q * 4 + 3, c3, n0)
      }
      #undef FLSTEP
    }
    #pragma unroll
    for (int o = 1; o < 64; o <<= 1) {
      double a = __shfl_down(s1, o, 64);
      double b = __shfl_down(s2, o, 64);
      double c = __shfl_down(s3, o, 64);
      double d = __shfl_down(s4, o, 64);
      if (lane + o < 64) { s1 += a; s2 += b; s3 += c; s4 += d; }
    }
    if (lane == 0) { tA[wv] = s1; tB[wv] = s2; tC[wv] = s3; tD[wv] = s4; }
    __syncthreads();   // orders publishes AND all cross-thread h/res reads above
    if (t == 0) {      // post flat partials + arrival -- NO WAIT (full-IMF lag)
      double S1 = 0.0, S2 = 0.0, S3 = 0.0, S4 = 0.0;
      for (int w = 0; w < NW; w++) { S1 += tA[w]; S2 += tB[w]; S3 += tC[w]; S4 += tD[w]; }
      atomicAdd(&flsl[k * 4 + 0], S1);
      atomicAdd(&flsl[k * 4 + 1], S2);
      atomicAdd(&flsl[k * 4 + 2], S3);
      atomicAdd(&flsl[k * 4 + 3], S4);
      __hip_atomic_fetch_add(&fcnt[k], 1u, __ATOMIC_ACQ_REL, __HIP_MEMORY_SCOPE_AGENT);
    }
    // outputs: IMF k = h; res -= h; h <- new res (current buffer)
    #pragma unroll
    for (int q = 0; q < NC / 4; q++) {
      int i0 = base + q * 4;
      int p0 = physi(i0);
      float4 rv = *(const float4*)&res[i0];
      float4 hv = *(const float4*)&hcur[p0];
      float4 rq = make_float4(rv.x - hv.x, rv.y - hv.y, rv.z - hv.z, rv.w - hv.w);
      *(float4*)&outk[i0] = hv;
      *(float4*)&res[i0] = rq;
      *(float4*)&hcur[p0] = rq;
    }
    __syncthreads();   // orders h <- res writes before next IMF's pass A
  }
}

extern "C" void kernel_launch(void* const* d_in, const int* in_sizes, int n_in,
                              void* d_out, int out_size, void* d_ws, size_t ws_size,
                              hipStream_t stream) {
  const float* x = (const float*)d_in[0];
  float* out = (float*)d_out;
  // ws: [0] scnt[72]; [512] sdsl[72][2]; [2048] fcnt[6]; [2304] flsl[6][4]
  size_t zb = ws_size < 4096 ? ws_size : 4096;
  hipMemsetAsync(d_ws, 0, zb, stream);
  hipLaunchKernelGGL(emd_main, dim3(NB), dim3(NT), 0, stream,
                     x, out, (char*)d_ws);
}